// Round 14
// baseline (105.300 us; speedup 1.0000x reference)
//
#include <hip/hip_runtime.h>
#include <hip/hip_bf16.h>
#include <math.h>

// VQ-VAE VectorQuantizer: B=32,T=2048,D=64,K=1024 -> N=65536 rows.
// Round 14: fused B-reuse x2 (R13 = 98.7us, absmax 0.0). Cross-round invariant:
// ~105cyc per 16x16 tile-unit = comparable MFMA issue + VALU tracking + 4KB
// B-frag L1 traffic. Fix: 64 rows/wave (4 row-tiles) halves L1-bytes and loop
// overhead per dot; med3 m2-update (-1 VALU/dist); 1-deep prefetch (300cyc
// body covers L2). A-frags may demote to AGPR -- free on gfx950 (MFMA reads
// AGPR natively). prep slimmed (keyBest init -> combine). Certificate math,
// combine tournament, exact scan, finalize: byte-frozen from R13.

typedef __attribute__((ext_vector_type(8))) short bf16x8;
typedef __attribute__((ext_vector_type(4))) float f32x4;

namespace {
constexpr int NROWS  = 65536;
constexpr int DDIM   = 64;
constexpr int KCODES = 1024;
constexpr float EPSB = 4e-5f;   // certificate band; bound ~1.05e-5

// ws layout (bytes) — ~7.6 MB
constexpr size_t WS_LOSS = 0;                            // double
constexpr size_t WS_CNT  = 64;                           // int
constexpr size_t WS_SE   = 256;                          // float[1024]
constexpr size_t WS_EHB  = 8192;                         // bf16 frags 128 KB
constexpr size_t WS_ELB  = WS_EHB + (size_t)65536 * 2;   // 128 KB
constexpr size_t WS_BIDX = WS_ELB + (size_t)65536 * 2;   // int[N]
constexpr size_t WS_LIST = WS_BIDX + (size_t)NROWS * 4;  // int[N]
constexpr size_t WS_KEY  = WS_LIST + (size_t)NROWS * 4;  // u64[N]
constexpr size_t WS_MV   = WS_KEY + (size_t)NROWS * 8;   // float2[4][N]
constexpr size_t WS_KV   = WS_MV + (size_t)4 * NROWS * 8; // u64[4][N]
}

__device__ inline short f2bf(float v) {
  __hip_bfloat16 h = __float2bfloat16(v);
  return *reinterpret_cast<short*>(&h);
}
__device__ inline float bf2f(short s) {
  __hip_bfloat16 h;
  *reinterpret_cast<short*>(&h) = s;
  return __bfloat162float(h);
}
__device__ inline f32x4 mfma16(bf16x8 a, bf16x8 b, f32x4 c) {
  return __builtin_amdgcn_mfma_f32_16x16x32_bf16(a, b, c, 0, 0, 0);
}
__device__ inline unsigned int fflip(unsigned int b) {
  return b ^ ((unsigned int)((int)b >> 31) | 0x80000000u);
}

// ---------------- prep: loss/cnt init, se (numpy pairwise), frag pack
__global__ __launch_bounds__(256) void vq_prep(const float* __restrict__ emb,
                                               float* __restrict__ se,
                                               short* __restrict__ ehB,
                                               short* __restrict__ elB,
                                               double* __restrict__ loss_accum,
                                               int* __restrict__ cnt) {
  #pragma clang fp contract(off)
  const int gid = blockIdx.x * 256 + (int)threadIdx.x;   // grid = 8192
  if (gid == 0) { *loss_accum = 0.0; *cnt = 0; }

  if (gid < KCODES) {   // se[j]: proven pairwise pattern
    const float* e = emb + (size_t)gid * DDIM;
    float r[8];
    #pragma unroll
    for (int j = 0; j < 8; ++j) r[j] = e[j] * e[j];
    #pragma unroll
    for (int i = 8; i < DDIM; i += 8) {
      #pragma unroll
      for (int j = 0; j < 8; ++j) r[j] += e[i + j] * e[i + j];
    }
    se[gid] = ((r[0] + r[1]) + (r[2] + r[3])) + ((r[4] + r[5]) + (r[6] + r[7]));
  }

  // pack frag (t,dc): lane l holds e[t*16+(l&15)][dc*32+(l>>4)*8 + i]  (R5-R13)
  {
    const int t  = gid >> 7;
    const int dc = (gid >> 6) & 1;
    const int l  = gid & 63;
    const int code = t * 16 + (l & 15);
    const int d0   = dc * 32 + (l >> 4) * 8;
    const float* ep = emb + (size_t)code * DDIM + d0;
    const size_t ob = ((size_t)(t * 2 + dc) * 64 + l) * 8;
    #pragma unroll
    for (int i = 0; i < 8; ++i) {
      const float v = ep[i];
      const short h = f2bf(v);
      ehB[ob + i] = h;
      elB[ob + i] = f2bf(v - bf2f(h));
    }
  }
}

// ---------------- fused sweep: block = 256 rows x 256 codes (4 row-tiles/wave)
__global__ __launch_bounds__(256, 2) void vq_fused(const float* __restrict__ x,
                                                   const short* __restrict__ ehB,
                                                   const short* __restrict__ elB,
                                                   const float* __restrict__ se,
                                                   float2* __restrict__ mv,
                                                   unsigned long long* __restrict__ kv) {
  #pragma clang fp contract(off)
  __shared__ float sel[256];                     // this quarter's se values
  const int tid  = (int)threadIdx.x;
  const int l    = tid & 63;
  const int wid  = tid >> 6;
  const int quar = (int)blockIdx.x & 3;          // K-quarter: tiles [q*16, q*16+16)
  const int rblk = (int)blockIdx.x >> 2;
  const int t0   = quar * 16;
  sel[tid] = se[t0 * 16 + tid];
  __syncthreads();

  // A-fragments for 4 row-tiles (64 rows/wave)
  const int wrb = rblk * 256 + wid * 64;
  bf16x8 xh[4][2], xl[4][2];
  #pragma unroll
  for (int rt = 0; rt < 4; ++rt) {
    const float* xp = x + (size_t)(wrb + rt * 16 + (l & 15)) * DDIM + (l >> 4) * 8;
    #pragma unroll
    for (int dc = 0; dc < 2; ++dc) {
      const float4 v0 = *reinterpret_cast<const float4*>(xp + dc * 32);
      const float4 v1 = *reinterpret_cast<const float4*>(xp + dc * 32 + 4);
      const float vv[8] = {v0.x, v0.y, v0.z, v0.w, v1.x, v1.y, v1.z, v1.w};
      #pragma unroll
      for (int i = 0; i < 8; ++i) {
        const short h = f2bf(vv[i]);
        xh[rt][dc][i] = h;
        xl[rt][dc][i] = f2bf(vv[i] - bf2f(h));
      }
    }
  }

  float m1v[4][4], m2v[4][4];
  int   m1t[4][4];
  #pragma unroll
  for (int rt = 0; rt < 4; ++rt)
    #pragma unroll
    for (int r = 0; r < 4; ++r) { m1v[rt][r] = INFINITY; m2v[rt][r] = INFINITY; m1t[rt][r] = 0; }

  const size_t lb = (size_t)l * 8;
#define FRAGLD(buf, tt, half2) \
  (*reinterpret_cast<const bf16x8*>((buf) + (size_t)(tt) * 1024 + (half2) * 512 + lb))

  // 1-deep prefetch: c* holds tile t, n* loads t+1 during compute.
  bf16x8 c0 = FRAGLD(ehB, t0, 0), c1 = FRAGLD(ehB, t0, 1),
         c2 = FRAGLD(elB, t0, 0), c3 = FRAGLD(elB, t0, 1);

  const f32x4 kz = {0.f, 0.f, 0.f, 0.f};
  #pragma unroll 4
  for (int tt = 0; tt < 16; ++tt) {
    const int t = t0 + tt;
    const int tf = (tt + 1 < 16) ? t + 1 : t;   // clamp (dup load harmless)
    bf16x8 n0 = FRAGLD(ehB, tf, 0), n1 = FRAGLD(ehB, tf, 1),
           n2 = FRAGLD(elB, tf, 0), n3 = FRAGLD(elB, tf, 1);

    f32x4 a0, a1, a2, a3;   // 4 row-tiles interleaved: dep distance 4
    a0 = mfma16(xh[0][0], c0, kz);  a1 = mfma16(xh[1][0], c0, kz);
    a2 = mfma16(xh[2][0], c0, kz);  a3 = mfma16(xh[3][0], c0, kz);
    a0 = mfma16(xh[0][1], c1, a0);  a1 = mfma16(xh[1][1], c1, a1);
    a2 = mfma16(xh[2][1], c1, a2);  a3 = mfma16(xh[3][1], c1, a3);
    a0 = mfma16(xh[0][0], c2, a0);  a1 = mfma16(xh[1][0], c2, a1);
    a2 = mfma16(xh[2][0], c2, a2);  a3 = mfma16(xh[3][0], c2, a3);
    a0 = mfma16(xh[0][1], c3, a0);  a1 = mfma16(xh[1][1], c3, a1);
    a2 = mfma16(xh[2][1], c3, a2);  a3 = mfma16(xh[3][1], c3, a3);
    a0 = mfma16(xl[0][0], c0, a0);  a1 = mfma16(xl[1][0], c0, a1);
    a2 = mfma16(xl[2][0], c0, a2);  a3 = mfma16(xl[3][0], c0, a3);
    a0 = mfma16(xl[0][1], c1, a0);  a1 = mfma16(xl[1][1], c1, a1);
    a2 = mfma16(xl[2][1], c1, a2);  a3 = mfma16(xl[3][1], c1, a3);

    const float sev = sel[tt * 16 + (l & 15)];
    #pragma unroll
    for (int r = 0; r < 4; ++r) {
      const float d0 = __builtin_fmaf(-2.0f, a0[r], sev);  // d' = se - 2*dot
      const float d1 = __builtin_fmaf(-2.0f, a1[r], sev);
      const float d2 = __builtin_fmaf(-2.0f, a2[r], sev);
      const float d3 = __builtin_fmaf(-2.0f, a3[r], sev);
      // m2 = median(m1, m2, d) == fmin(m2, fmax(m1, d)) given m1<=m2
      m2v[0][r] = __builtin_amdgcn_fmed3f(m1v[0][r], m2v[0][r], d0);
      m1t[0][r] = (d0 < m1v[0][r]) ? t : m1t[0][r];
      m1v[0][r] = fminf(m1v[0][r], d0);
      m2v[1][r] = __builtin_amdgcn_fmed3f(m1v[1][r], m2v[1][r], d1);
      m1t[1][r] = (d1 < m1v[1][r]) ? t : m1t[1][r];
      m1v[1][r] = fminf(m1v[1][r], d1);
      m2v[2][r] = __builtin_amdgcn_fmed3f(m1v[2][r], m2v[2][r], d2);
      m1t[2][r] = (d2 < m1v[2][r]) ? t : m1t[2][r];
      m1v[2][r] = fminf(m1v[2][r], d2);
      m2v[3][r] = __builtin_amdgcn_fmed3f(m1v[3][r], m2v[3][r], d3);
      m1t[3][r] = (d3 < m1v[3][r]) ? t : m1t[3][r];
      m1v[3][r] = fminf(m1v[3][r], d3);
    }
    c0 = n0; c1 = n1; c2 = n2; c3 = n3;
  }
#undef FRAGLD

  // 16-lane merge (R6-R13-proven); emit per-quarter partials
  const int colbase = l & 15;
  #pragma unroll
  for (int rt = 0; rt < 4; ++rt) {
    #pragma unroll
    for (int r = 0; r < 4; ++r) {
      float m1 = m1v[rt][r], m2 = m2v[rt][r];
      unsigned long long key =
          ((unsigned long long)fflip(__float_as_uint(m1)) << 32)
          | (unsigned)(m1t[rt][r] * 16 + colbase);
      #pragma unroll
      for (int off = 1; off < 16; off <<= 1) {
        const unsigned long long ok = __shfl_xor(key, off, 16);
        const float om1 = __shfl_xor(m1, off, 16);
        const float om2 = __shfl_xor(m2, off, 16);
        m2 = fminf(fminf(m2, om2), fmaxf(m1, om1));
        m1 = fminf(m1, om1);
        key = (ok < key) ? ok : key;
      }
      if (colbase == 0) {
        const int row = wrb + rt * 16 + (l >> 4) * 4 + r;
        mv[(size_t)quar * NROWS + row] = make_float2(m1, m2);
        kv[(size_t)quar * NROWS + row] = key;
      }
    }
  }
}

// ---------------- combine 4 quarters + certificate + compaction + keyBest init
__global__ __launch_bounds__(256) void vq_combine(const float2* __restrict__ mv,
                                                  const unsigned long long* __restrict__ kv,
                                                  int* __restrict__ bidx,
                                                  int* __restrict__ list,
                                                  int* __restrict__ cnt,
                                                  unsigned long long* __restrict__ keyBest) {
  const int gid = blockIdx.x * 256 + (int)threadIdx.x;
  const int l = (int)threadIdx.x & 63;
  keyBest[gid] = ~0ull;
  const float2 A = mv[gid];
  const float2 B = mv[(size_t)NROWS + gid];
  const float2 C = mv[(size_t)2 * NROWS + gid];
  const float2 D = mv[(size_t)3 * NROWS + gid];
  unsigned long long kg = kv[gid];
  {
    unsigned long long k2 = kv[(size_t)NROWS + gid];     kg = (k2 < kg) ? k2 : kg;
    k2 = kv[(size_t)2 * NROWS + gid];                    kg = (k2 < kg) ? k2 : kg;
    k2 = kv[(size_t)3 * NROWS + gid];                    kg = (k2 < kg) ? k2 : kg;
  }
  // union's two smallest over 4 disjoint quarters (exact tournament rule)
  const float lo1 = fminf(A.x, B.x), hi1 = fmaxf(A.x, B.x);
  const float lo2 = fminf(C.x, D.x), hi2 = fmaxf(C.x, D.x);
  const float m1g = fminf(lo1, lo2);
  const float sec = fminf(fmaxf(lo1, lo2), fminf(hi1, hi2));  // secondmin{m1}
  const float m2g = fminf(sec, fminf(fminf(A.y, B.y), fminf(C.y, D.y)));
  const bool cert = m2g > m1g + EPSB;
  bidx[gid] = cert ? (int)(kg & 0xffffffffull) : -1;

  const unsigned long long mask = __ballot(!cert);
  int base = 0;
  if (l == 0 && mask) base = atomicAdd(cnt, (int)__popcll(mask));
  base = __shfl(base, 0, 64);
  if (!cert) {
    const int off = (int)__popcll(mask & ((1ull << l) - 1ull));
    list[base + off] = gid;
  }
}

// ---------------- exact scan: 1-wave blocks, lanes = rows, 32-code LDS parts,
// grid-strided tasks (R13-frozen). Per-(row,code) arithmetic verbatim R11-R13.
__global__ __launch_bounds__(64) void vq_exact(const float* __restrict__ x,
                                               const float* __restrict__ emb,
                                               const float* __restrict__ se,
                                               const int* __restrict__ list,
                                               const int* __restrict__ cnt,
                                               unsigned long long* __restrict__ keyBest) {
  #pragma clang fp contract(off)
  __shared__ __align__(16) float eL[32 * DDIM];   // 8 KB: one part's 32 codes
  const int n = *cnt;
  if (n == 0) return;
  const int nrb = (n + 63) >> 6;
  const int ntasks = nrb * 32;
  const int l = (int)threadIdx.x;                 // 0..63

  for (int t = (int)blockIdx.x; t < ntasks; t += (int)gridDim.x) {
    const int part = t & 31;
    const int rb   = t >> 5;
    const int j0   = part * 32;

    {  // stage this part's 32 e-rows (coalesced float4)
      const float4* src = reinterpret_cast<const float4*>(emb + (size_t)j0 * DDIM);
      float4* dst = reinterpret_cast<float4*>(eL);
      #pragma unroll
      for (int i = 0; i < 8; ++i) dst[i * 64 + l] = src[i * 64 + l];
    }
    __syncthreads();

    const int idx = rb * 64 + l;
    const bool act = idx < n;
    const int row = act ? list[idx] : 0;
    const float4* xr4 = reinterpret_cast<const float4*>(x + (size_t)row * DDIM);

    float xv[DDIM];   // x row -> regs once
    #pragma unroll
    for (int q = 0; q < 16; ++q) {
      const float4 v = xr4[q];
      xv[q * 4 + 0] = v.x; xv[q * 4 + 1] = v.y;
      xv[q * 4 + 2] = v.z; xv[q * 4 + 3] = v.w;
    }

    // sx: numpy pairwise 8-accumulator (R1-proven order)
    float rr[8];
    #pragma unroll
    for (int j = 0; j < 8; ++j) rr[j] = xv[j] * xv[j];
    #pragma unroll
    for (int i = 8; i < DDIM; i += 8) {
      #pragma unroll
      for (int j = 0; j < 8; ++j) rr[j] += xv[i + j] * xv[i + j];
    }
    const float sx = ((rr[0] + rr[1]) + (rr[2] + rr[3])) + ((rr[4] + rr[5]) + (rr[6] + rr[7]));

    unsigned long long best = ~0ull;
    #pragma unroll 1
    for (int g = 0; g < 8; ++g) {   // 8 groups of 4 codes; 4 chains
      const int jb = g * 4;
      const float4* e0 = reinterpret_cast<const float4*>(eL + (jb + 0) * DDIM);
      const float4* e1 = reinterpret_cast<const float4*>(eL + (jb + 1) * DDIM);
      const float4* e2 = reinterpret_cast<const float4*>(eL + (jb + 2) * DDIM);
      const float4* e3 = reinterpret_cast<const float4*>(eL + (jb + 3) * DDIM);
      float a0 = 0.f, a1 = 0.f, a2 = 0.f, a3 = 0.f;
      #pragma unroll
      for (int q = 0; q < 16; ++q) {   // per code: sequential d=0..63 (R1 chain)
        const float4 v0 = e0[q], v1 = e1[q], v2 = e2[q], v3 = e3[q];
        const float xa = xv[q * 4 + 0], xb = xv[q * 4 + 1];
        const float xc = xv[q * 4 + 2], xd = xv[q * 4 + 3];
        a0 = __builtin_fmaf(xa, v0.x, a0); a0 = __builtin_fmaf(xb, v0.y, a0);
        a0 = __builtin_fmaf(xc, v0.z, a0); a0 = __builtin_fmaf(xd, v0.w, a0);
        a1 = __builtin_fmaf(xa, v1.x, a1); a1 = __builtin_fmaf(xb, v1.y, a1);
        a1 = __builtin_fmaf(xc, v1.z, a1); a1 = __builtin_fmaf(xd, v1.w, a1);
        a2 = __builtin_fmaf(xa, v2.x, a2); a2 = __builtin_fmaf(xb, v2.y, a2);
        a2 = __builtin_fmaf(xc, v2.z, a2); a2 = __builtin_fmaf(xd, v2.w, a2);
        a3 = __builtin_fmaf(xa, v3.x, a3); a3 = __builtin_fmaf(xb, v3.y, a3);
        a3 = __builtin_fmaf(xc, v3.z, a3); a3 = __builtin_fmaf(xd, v3.w, a3);
      }
      const int j = j0 + jb;
      const float T0 = sx + se[j + 0];                    // fl(sx + se_j)
      const float T1 = sx + se[j + 1];
      const float T2 = sx + se[j + 2];
      const float T3 = sx + se[j + 3];
      const float di0 = __builtin_fmaf(-2.0f, a0, T0);    // fl(T - 2*acc)
      const float di1 = __builtin_fmaf(-2.0f, a1, T1);
      const float di2 = __builtin_fmaf(-2.0f, a2, T2);
      const float di3 = __builtin_fmaf(-2.0f, a3, T3);
      unsigned long long k;
      k = ((unsigned long long)fflip(__float_as_uint(di0)) << 32) | (unsigned)(j + 0);
      best = (k < best) ? k : best;
      k = ((unsigned long long)fflip(__float_as_uint(di1)) << 32) | (unsigned)(j + 1);
      best = (k < best) ? k : best;
      k = ((unsigned long long)fflip(__float_as_uint(di2)) << 32) | (unsigned)(j + 2);
      best = (k < best) ? k : best;
      k = ((unsigned long long)fflip(__float_as_uint(di3)) << 32) | (unsigned)(j + 3);
      best = (k < best) ? k : best;
    }
    if (act) atomicMin(&keyBest[row], best);   // (dist asc, j asc) == first-min
    __syncthreads();                           // eL reuse barrier (1-wave: cheap)
  }
}

// ---------------- finalize: 16 lanes x float4 per row (coalesced e-gather)
__global__ __launch_bounds__(256) void vq_finalize(const float* __restrict__ x,
                                                   const float* __restrict__ emb,
                                                   const int* __restrict__ bidx,
                                                   const unsigned long long* __restrict__ keyBest,
                                                   float* __restrict__ out,
                                                   double* __restrict__ loss_accum) {
  #pragma clang fp contract(off)
  __shared__ float wsum[4];
  const int tid = (int)threadIdx.x;
  const int l   = tid & 63;
  const int wid = tid >> 6;
  const int sub = l >> 4;    // row within the wave's quad
  const int q16 = l & 15;    // float4 slot within the row
  float lacc = 0.f;

  #pragma unroll
  for (int it = 0; it < 4; ++it) {   // block covers 64 rows
    const int row = blockIdx.x * 64 + it * 16 + wid * 4 + sub;
    int bi = bidx[row];
    if (bi < 0) bi = (int)(keyBest[row] & 0xffffffffull);
    const float4 xv = reinterpret_cast<const float4*>(x)[(size_t)row * 16 + q16];
    const float4 ev = reinterpret_cast<const float4*>(emb)[(size_t)bi * 16 + q16];
    const float da = ev.x - xv.x;
    const float db = ev.y - xv.y;
    const float dc = ev.z - xv.z;
    const float dd = ev.w - xv.w;
    float4 o;
    o.x = xv.x + da; o.y = xv.y + db; o.z = xv.z + dc; o.w = xv.w + dd;
    reinterpret_cast<float4*>(out)[(size_t)row * 16 + q16] = o;
    lacc += da * da + db * db + dc * dc + dd * dd;   // order-insensitive
    if (q16 == 0) out[(size_t)NROWS * DDIM + row] = (float)bi;
  }
  #pragma unroll
  for (int off = 32; off > 0; off >>= 1) lacc += __shfl_down(lacc, off, 64);
  if (l == 0) wsum[wid] = lacc;
  __syncthreads();
  if (tid == 0)
    atomicAdd(loss_accum, (double)(wsum[0] + wsum[1] + wsum[2] + wsum[3]));
}

// ---------------- scalars
__global__ void vq_scalars(const double* __restrict__ loss_accum,
                           float* __restrict__ out) {
  if (threadIdx.x == 0 && blockIdx.x == 0) {
    const double mm = *loss_accum / (double)((size_t)NROWS * DDIM);
    const float el = (float)mm;
    float* tail = out + (size_t)NROWS * DDIM + NROWS;
    tail[0] = 0.25f * el;
    tail[1] = el;
    tail[2] = 0.0f;
  }
}

// ============================================================================
extern "C" void kernel_launch(void* const* d_in, const int* in_sizes, int n_in,
                              void* d_out, int out_size, void* d_ws, size_t ws_size,
                              hipStream_t stream) {
  const float* x   = (const float*)d_in[0];  // [N, 64]
  const float* emb = (const float*)d_in[1];  // [K, 64]
  float* out = (float*)d_out;
  char* ws = (char*)d_ws;

  double* loss_accum = (double*)(ws + WS_LOSS);
  int*    cnt        = (int*)(ws + WS_CNT);
  float*  se         = (float*)(ws + WS_SE);
  short*  ehB        = (short*)(ws + WS_EHB);
  short*  elB        = (short*)(ws + WS_ELB);
  int*    bidx       = (int*)(ws + WS_BIDX);
  int*    list       = (int*)(ws + WS_LIST);
  unsigned long long* keyBest = (unsigned long long*)(ws + WS_KEY);
  float2* mv         = (float2*)(ws + WS_MV);
  unsigned long long* kv = (unsigned long long*)(ws + WS_KV);

  vq_prep<<<32, 256, 0, stream>>>(emb, se, ehB, elB, loss_accum, cnt);
  vq_fused<<<(NROWS / 256) * 4, 256, 0, stream>>>(x, ehB, elB, se, mv, kv);
  vq_combine<<<NROWS / 256, 256, 0, stream>>>(mv, kv, bidx, list, cnt, keyBest);
  vq_exact<<<2048, 64, 0, stream>>>(x, emb, se, list, cnt, keyBest);
  vq_finalize<<<NROWS / 64, 256, 0, stream>>>(x, emb, bidx, keyBest, out,
                                              loss_accum);
  vq_scalars<<<1, 64, 0, stream>>>(loss_accum, out);
}